// Round 6
// baseline (126.788 us; speedup 1.0000x reference)
//
#include <hip/hip_runtime.h>

// Causal dilated conv1d (dilation=64, K=2) + tanh*sigmoid gate via bf16 MFMA.
// v5 (resubmit — prior round was an infra failure, not a kernel verdict):
// 3-bank LDS pipeline, ONE barrier per 64-t chunk, full-iteration memory cover.
//   Theory: v1-v4 all plateau at 2.5-2.9 TB/s because phases convoy: every
//   __syncthreads drains vmcnt(0), and v4 had two per chunk with < HBM-latency
//   cover. v5: per iteration k: issue loads window k+3 -> regs; epilogue
//   stores chunk k-1; ds_write window k+2 (regs loaded a FULL iteration ago);
//   compute chunk k from banks k%3,(k+1)%3 (disjoint from written bank
//   (k+2)%3 -> no write/compute barrier); single __syncthreads.
//   Banks: 3 x 64 rows x 64 ci bf16 = 24 KB. Window w = rows
//   [t0-64+64w, t0+64w), bank w%3. Chunk k reads windows k (tap0) and k+1 (tap1).
// Epilogue: tanh(y)*sigmoid(y) = (1-u)/(1+u^2), u = e^-y  (algebraic identity,
//   7 ops vs 10). Transposed-output MFMA (A=x,B=w) -> float4 stores (v4).
// w split hi/lo (2 MFMA terms, fp32-grade w); x single RNE bf16.
// y[b,co,t] = sum_ci w[co][ci][0]*x[b][ci][t-64] + w[co][ci][1]*x[b][ci][t]

#define B_ 16
#define C_ 64
#define T_ 16384

typedef __attribute__((ext_vector_type(8))) short short8;
typedef __attribute__((ext_vector_type(4))) float f32x4;

union Frag { short8 s; unsigned u[4]; };

__device__ __forceinline__ unsigned bf16_rne(float f) {
    unsigned u = __float_as_uint(f);
    return (u + 0x7fffu + ((u >> 16) & 1u)) >> 16;
}

__device__ __forceinline__ unsigned pack_rne(float a, float b) {
    unsigned ua = __float_as_uint(a), ub = __float_as_uint(b);
    unsigned ra = ua + 0x7fffu + ((ua >> 16) & 1u);
    unsigned rb = ub + 0x7fffu + ((ub >> 16) & 1u);
    return (ra >> 16) | (rb & 0xffff0000u);
}

// Gate + store for chunk KK. Lane (m,q) holds t = KK*64+16s+4q+r of out row
// co = wid*16+m (transposed D). tanh(y)*sigmoid(y) = (1-u)/(1+u^2), u=e^-y.
#define EPILOGUE(A, KK)                                                     \
    _Pragma("unroll")                                                       \
    for (int s = 0; s < 4; ++s) {                                           \
        float4 o4;                                                          \
        _Pragma("unroll")                                                   \
        for (int r = 0; r < 4; ++r) {                                       \
            float y = fmaxf((A)[s][r], -30.f);                              \
            float u = __expf(-y);                                           \
            ((float*)&o4)[r] = (1.f - u) *                                  \
                __builtin_amdgcn_rcpf(__builtin_fmaf(u, u, 1.f));           \
        }                                                                   \
        *(float4*)(ob + (KK) * 64 + 16 * s + 4 * q) = o4;                   \
    }

__global__ __launch_bounds__(256, 4) void conv_gate_pipe(
    const float* __restrict__ x,
    const float* __restrict__ w,
    float* __restrict__ out)
{
    __shared__ unsigned short xs[3 * 64 * 64];   // 3 banks * 8 KB = 24576 B

    const int tid = threadIdx.x;
    const int bid = blockIdx.x;
    // XCD-bijective swizzle (1024 wgs, 8 XCDs).
    const int wg  = (bid & 7) * 128 + (bid >> 3);
    const int b   = wg >> 6;          // batch
    const int seg = wg & 63;          // 256-t segment
    const int t0  = seg << 8;
    const float* xb = x + (size_t)b * C_ * T_;

    // ---- prologue A: issue loads for windows 0,1 (rows [t0-64, t0+64))
    float pv[4][8];
    #pragma unroll
    for (int it = 0; it < 4; ++it) {
        const int task = it * 256 + tid;
        const int rr   = task & 127;
        const int c8   = task >> 7;          // 0..7
        const int g    = t0 - 64 + rr;
        if (g >= 0) {
            const float* xp = xb + (size_t)(8 * c8) * T_ + g;
            #pragma unroll
            for (int i = 0; i < 8; ++i) pv[it][i] = xp[(size_t)i * T_];
        } else {
            #pragma unroll
            for (int i = 0; i < 8; ++i) pv[it][i] = 0.f;
        }
    }

    // ---- prologue B: issue loads for window 2 (rows [t0+64, t0+128))
    float vbuf[2][2][8];
    #pragma unroll
    for (int it = 0; it < 2; ++it) {
        const int task = it * 256 + tid;
        const int rr = task & 63, c8 = task >> 6;
        const float* xp = xb + (size_t)(8 * c8) * T_ + (t0 + 64 + rr);
        #pragma unroll
        for (int i = 0; i < 8; ++i) vbuf[0][it][i] = xp[(size_t)i * T_];
    }

    // ---- per-wave w fragments, hi/lo RNE split (same bytes serve as B-operand)
    const int lane = tid & 63;
    const int wid  = tid >> 6;
    const int m    = lane & 15;
    const int q    = lane >> 4;
    const int co   = wid * 16 + m;

    Frag wh[2][2], wl[2][2];   // [tap p][k-half h]
    #pragma unroll
    for (int h = 0; h < 2; ++h) {
        const float* wp = w + co * 128 + h * 64 + q * 16;
        float f[16];
        #pragma unroll
        for (int v4 = 0; v4 < 4; ++v4) {
            float4 t4 = *(const float4*)(wp + 4 * v4);
            f[4*v4+0] = t4.x; f[4*v4+1] = t4.y; f[4*v4+2] = t4.z; f[4*v4+3] = t4.w;
        }
        #pragma unroll
        for (int p = 0; p < 2; ++p) {
            #pragma unroll
            for (int d = 0; d < 4; ++d) {
                float e0 = f[2*(2*d)   + p];
                float e1 = f[2*(2*d+1) + p];
                unsigned h0 = bf16_rne(e0), h1 = bf16_rne(e1);
                float r0 = e0 - __uint_as_float(h0 << 16);
                float r1 = e1 - __uint_as_float(h1 << 16);
                wh[p][h].u[d] = h0 | (h1 << 16);
                wl[p][h].u[d] = bf16_rne(r0) | (bf16_rne(r1) << 16);
            }
        }
    }

    // ---- prologue C: pack + write windows 0,1 into banks 0,1
    #pragma unroll
    for (int it = 0; it < 4; ++it) {
        const int task = it * 256 + tid;
        const int rr   = task & 127;
        const int c8   = task >> 7;
        unsigned p0 = pack_rne(pv[it][0], pv[it][1]);
        unsigned p1 = pack_rne(pv[it][2], pv[it][3]);
        unsigned p2 = pack_rne(pv[it][4], pv[it][5]);
        unsigned p3 = pack_rne(pv[it][6], pv[it][7]);
        const int so = (rr >> 6) * 4096 + (rr & 63) * 64 + ((c8 ^ (rr & 7)) * 8);
        *(uint4*)(&xs[so]) = make_uint4(p0, p1, p2, p3);
    }

    const int n   = m;
    const int swb = n & 7;
    float* ob = out + ((size_t)b * C_ + wid * 16 + m) * T_ + t0;   // transposed row

    f32x4 acc2[2][4];

    __syncthreads();

    // ---- 4 chunks of 64 t, one barrier each.
    #pragma unroll
    for (int k = 0; k < 4; ++k) {
        // (1) issue loads for window k+3 (rows [t0+64(k+2), +64))
        if (k <= 1) {
            #pragma unroll
            for (int it = 0; it < 2; ++it) {
                const int task = it * 256 + tid;
                const int rr = task & 63, c8 = task >> 6;
                const float* xp = xb + (size_t)(8 * c8) * T_ + (t0 + 64 * (k + 2) + rr);
                #pragma unroll
                for (int i = 0; i < 8; ++i) vbuf[(k + 1) & 1][it][i] = xp[(size_t)i * T_];
            }
        }

        // (2) deferred epilogue of chunk k-1: stores get compute-phase cover
        if (k >= 1) { EPILOGUE(acc2[(k & 1) ^ 1], k - 1); }

        // (3) ds_write window k+2 into bank (k+2)%3 (regs loaded a full iter ago;
        //     disjoint from the banks chunk k reads -> no barrier before compute)
        if (k <= 2) {
            #pragma unroll
            for (int it = 0; it < 2; ++it) {
                const int task = it * 256 + tid;
                const int rr = task & 63, c8 = task >> 6;
                unsigned p0 = pack_rne(vbuf[k & 1][it][0], vbuf[k & 1][it][1]);
                unsigned p1 = pack_rne(vbuf[k & 1][it][2], vbuf[k & 1][it][3]);
                unsigned p2 = pack_rne(vbuf[k & 1][it][4], vbuf[k & 1][it][5]);
                unsigned p3 = pack_rne(vbuf[k & 1][it][6], vbuf[k & 1][it][7]);
                const int so = ((k + 2) % 3) * 4096 + rr * 64 + ((c8 ^ (rr & 7)) * 8);
                *(uint4*)(&xs[so]) = make_uint4(p0, p1, p2, p3);
            }
        }

        // (4) compute chunk k: windows k (tap0) and k+1 (tap1), banks k%3,(k+1)%3
        f32x4* acc = acc2[k & 1];
        #pragma unroll
        for (int s = 0; s < 4; ++s) acc[s] = (f32x4){0.f, 0.f, 0.f, 0.f};
        #pragma unroll
        for (int u = 0; u < 8; ++u) {
            const int wnd   = k + (u >> 2);            // compile-time
            const int rbase = (wnd % 3) * 4096 + (16 * (u & 3) + n) * 64;
            Frag f0, f1;
            f0.s = *(const short8*)(&xs[rbase + ((q ^ swb) * 8)]);        // ci 8q..
            f1.s = *(const short8*)(&xs[rbase + (((4 + q) ^ swb) * 8)]);  // ci 32+8q..
            if (u < 4) {
                acc[u] = __builtin_amdgcn_mfma_f32_16x16x32_bf16(f0.s, wh[0][0].s, acc[u], 0, 0, 0);
                acc[u] = __builtin_amdgcn_mfma_f32_16x16x32_bf16(f0.s, wl[0][0].s, acc[u], 0, 0, 0);
                acc[u] = __builtin_amdgcn_mfma_f32_16x16x32_bf16(f1.s, wh[0][1].s, acc[u], 0, 0, 0);
                acc[u] = __builtin_amdgcn_mfma_f32_16x16x32_bf16(f1.s, wl[0][1].s, acc[u], 0, 0, 0);
            } else {
                const int s2 = u - 4;
                acc[s2] = __builtin_amdgcn_mfma_f32_16x16x32_bf16(f0.s, wh[1][0].s, acc[s2], 0, 0, 0);
                acc[s2] = __builtin_amdgcn_mfma_f32_16x16x32_bf16(f0.s, wl[1][0].s, acc[s2], 0, 0, 0);
                acc[s2] = __builtin_amdgcn_mfma_f32_16x16x32_bf16(f1.s, wh[1][1].s, acc[s2], 0, 0, 0);
                acc[s2] = __builtin_amdgcn_mfma_f32_16x16x32_bf16(f1.s, wl[1][1].s, acc[s2], 0, 0, 0);
            }
        }

        // (5) single barrier: window-k readers done before bank (k+3)%3=k%3 is
        //     overwritten next iter; this iter's ds_write visible for chunk k+1.
        if (k < 3) __syncthreads();
    }

    EPILOGUE(acc2[1], 3);
}

extern "C" void kernel_launch(void* const* d_in, const int* in_sizes, int n_in,
                              void* d_out, int out_size, void* d_ws, size_t ws_size,
                              hipStream_t stream) {
    const float* x = (const float*)d_in[0];
    const float* w = (const float*)d_in[1];
    float* out = (float*)d_out;
    conv_gate_pipe<<<dim3(1024), dim3(256), 0, stream>>>(x, w, out);
}

// Round 7
// 123.780 us; speedup vs baseline: 1.0243x; 1.0243x over previous
//
#include <hip/hip_runtime.h>

// Causal dilated conv1d (dilation=64, K=2) + tanh*sigmoid gate via bf16 MFMA.
// v6 = v5 (3-bank ring, 1 barrier/chunk) + WIDE LOADS (global_load_dwordx4).
//   Theory: all prior versions load x as 4 B/lane dwords (256 B/wave-inst) —
//   the measured 2.4 TB/s scalar regime (RMSNorm m146: 4B/lane=2.35 TB/s,
//   16B/lane=4.89 TB/s, same coalescing). v6 re-maps staging so each thread
//   loads 4 float4 (16 B/lane, 1 KB/wave-inst): thread owns 4 consecutive t
//   x 4 ci; in-register transpose -> 4x 8-B LDS writes into the SAME
//   XOR-swizzled layout the MFMA fragment reads expect (read side unchanged).
//   VMEM insts/thread/chunk: 20 -> 8, all 16 B/lane.
// Ring: 3 banks x 64 rows x 64 ci bf16 = 24 KB; window w = rows
//   [t0-64+64w, t0+64w), bank w%3; chunk k reads windows k,k+1, writes w(k+2).
// Epilogue: tanh(y)*sigmoid(y) = (1-u)/(1+u^2), u=e^-y; transposed-output
//   MFMA (A=x,B=w) -> float4 stores; deferred one chunk for store cover.
// w split hi/lo (2 MFMA terms, fp32-grade w); x single RNE bf16.
// y[b,co,t] = sum_ci w[co][ci][0]*x[b][ci][t-64] + w[co][ci][1]*x[b][ci][t]

#define B_ 16
#define C_ 64
#define T_ 16384

typedef __attribute__((ext_vector_type(8))) short short8;
typedef __attribute__((ext_vector_type(4))) float f32x4;

union Frag { short8 s; unsigned u[4]; };

__device__ __forceinline__ unsigned bf16_rne(float f) {
    unsigned u = __float_as_uint(f);
    return (u + 0x7fffu + ((u >> 16) & 1u)) >> 16;
}

__device__ __forceinline__ unsigned pack_rne(float a, float b) {
    unsigned ua = __float_as_uint(a), ub = __float_as_uint(b);
    unsigned ra = ua + 0x7fffu + ((ua >> 16) & 1u);
    unsigned rb = ub + 0x7fffu + ((ub >> 16) & 1u);
    return (ra >> 16) | (rb & 0xffff0000u);
}

// Gate + store for chunk KK (transposed D): lane (m,q) holds t = KK*64+16s+4q+r
// of out row co = wid*16+m. tanh(y)*sigmoid(y) = (1-u)/(1+u^2), u=e^-y.
#define EPILOGUE(A, KK)                                                     \
    _Pragma("unroll")                                                       \
    for (int s = 0; s < 4; ++s) {                                           \
        float4 o4;                                                          \
        _Pragma("unroll")                                                   \
        for (int r = 0; r < 4; ++r) {                                       \
            float y = fmaxf((A)[s][r], -30.f);                              \
            float u = __expf(-y);                                           \
            ((float*)&o4)[r] = (1.f - u) *                                  \
                __builtin_amdgcn_rcpf(__builtin_fmaf(u, u, 1.f));           \
        }                                                                   \
        *(float4*)(ob + (KK) * 64 + 16 * s + 4 * q) = o4;                   \
    }

// In-register transpose of 4 float4 (4 ci rows x 4 t) -> 4x 8-B LDS writes.
// Row rr = 4*tq+e, 16-B slot (c4>>1)^(rr&7), half-slot (c4&1)*4 shorts.
// Read side (slot = c8 ^ (rr&7), ci-ordered shorts) is byte-identical to v5.
#define STAGE_WRITE(F, BANK)                                                \
    _Pragma("unroll")                                                       \
    for (int e = 0; e < 4; ++e) {                                           \
        const int rr = 4 * tq + e;                                          \
        const int so = (BANK) * 4096 + rr * 64 +                            \
                       (((c4 >> 1) ^ (rr & 7)) * 8) + ((c4 & 1) * 4);       \
        unsigned u0 = pack_rne(((const float*)&(F)[0])[e],                  \
                               ((const float*)&(F)[1])[e]);                 \
        unsigned u1 = pack_rne(((const float*)&(F)[2])[e],                  \
                               ((const float*)&(F)[3])[e]);                 \
        *(uint2*)(&xs[so]) = make_uint2(u0, u1);                            \
    }

__global__ __launch_bounds__(256, 4) void conv_gate_wide(
    const float* __restrict__ x,
    const float* __restrict__ w,
    float* __restrict__ out)
{
    __shared__ unsigned short xs[3 * 64 * 64];   // 3 banks * 8 KB = 24576 B

    const int tid = threadIdx.x;
    const int bid = blockIdx.x;
    // XCD-bijective swizzle (1024 wgs, 8 XCDs).
    const int wg  = (bid & 7) * 128 + (bid >> 3);
    const int b   = wg >> 6;          // batch
    const int seg = wg & 63;          // 256-t segment
    const int t0  = seg << 8;
    const float* xb = x + (size_t)b * C_ * T_;

    // staging task: thread owns ci quad 4*c4..+3, t quad 4*tq..+3
    const int c4 = tid >> 4;          // 0..15
    const int tq = tid & 15;          // 0..15
    const float* xgb = xb + (size_t)(4 * c4) * T_ + 4 * tq;

    // ---- prologue: wide loads for windows 0 and 1 (overlapped latencies)
    float4 fa[4], fb[4];
    if (seg > 0) {
        #pragma unroll
        for (int i = 0; i < 4; ++i)
            fa[i] = *(const float4*)(xgb + (size_t)i * T_ + (t0 - 64));
    } else {
        #pragma unroll
        for (int i = 0; i < 4; ++i) fa[i] = make_float4(0.f, 0.f, 0.f, 0.f);
    }
    #pragma unroll
    for (int i = 0; i < 4; ++i)
        fb[i] = *(const float4*)(xgb + (size_t)i * T_ + t0);

    // ---- per-wave w fragments, hi/lo RNE split (overlaps x latency)
    const int lane = tid & 63;
    const int wid  = tid >> 6;
    const int m    = lane & 15;
    const int q    = lane >> 4;
    const int co   = wid * 16 + m;

    Frag wh[2][2], wl[2][2];   // [tap p][k-half h]
    #pragma unroll
    for (int h = 0; h < 2; ++h) {
        const float* wp = w + co * 128 + h * 64 + q * 16;
        float f[16];
        #pragma unroll
        for (int v4 = 0; v4 < 4; ++v4) {
            float4 t4 = *(const float4*)(wp + 4 * v4);
            f[4*v4+0] = t4.x; f[4*v4+1] = t4.y; f[4*v4+2] = t4.z; f[4*v4+3] = t4.w;
        }
        #pragma unroll
        for (int p = 0; p < 2; ++p) {
            #pragma unroll
            for (int d = 0; d < 4; ++d) {
                float e0 = f[2*(2*d)   + p];
                float e1 = f[2*(2*d+1) + p];
                unsigned h0 = bf16_rne(e0), h1 = bf16_rne(e1);
                float r0 = e0 - __uint_as_float(h0 << 16);
                float r1 = e1 - __uint_as_float(h1 << 16);
                wh[p][h].u[d] = h0 | (h1 << 16);
                wl[p][h].u[d] = bf16_rne(r0) | (bf16_rne(r1) << 16);
            }
        }
    }

    // ---- prologue: transpose+write windows 0,1 into banks 0,1
    STAGE_WRITE(fa, 0)
    STAGE_WRITE(fb, 1)

    const int n   = m;
    const int swb = n & 7;
    float* ob = out + ((size_t)b * C_ + wid * 16 + m) * T_ + t0;   // transposed row

    f32x4 acc2[2][4];

    __syncthreads();

    // ---- 4 chunks of 64 t, one barrier each.
    #pragma unroll
    for (int k = 0; k < 4; ++k) {
        // (1) issue WIDE loads for window k+2 (rows [t0+64(k+1), +64));
        //     consumed after compute -> full epilogue+compute phase of cover
        float4 fv[4];
        if (k <= 2) {
            #pragma unroll
            for (int i = 0; i < 4; ++i)
                fv[i] = *(const float4*)(xgb + (size_t)i * T_ + (t0 + 64 * (k + 1)));
        }

        // (2) deferred epilogue of chunk k-1: stores get compute-phase cover
        if (k >= 1) { EPILOGUE(acc2[(k & 1) ^ 1], k - 1); }

        // (3) compute chunk k: windows k (tap0), k+1 (tap1) in banks k%3,(k+1)%3
        f32x4* acc = acc2[k & 1];
        #pragma unroll
        for (int s = 0; s < 4; ++s) acc[s] = (f32x4){0.f, 0.f, 0.f, 0.f};
        #pragma unroll
        for (int u = 0; u < 8; ++u) {
            const int wnd   = k + (u >> 2);            // compile-time
            const int rbase = (wnd % 3) * 4096 + (16 * (u & 3) + n) * 64;
            Frag f0, f1;
            f0.s = *(const short8*)(&xs[rbase + ((q ^ swb) * 8)]);        // ci 8q..
            f1.s = *(const short8*)(&xs[rbase + (((4 + q) ^ swb) * 8)]);  // ci 32+8q..
            if (u < 4) {
                acc[u] = __builtin_amdgcn_mfma_f32_16x16x32_bf16(f0.s, wh[0][0].s, acc[u], 0, 0, 0);
                acc[u] = __builtin_amdgcn_mfma_f32_16x16x32_bf16(f0.s, wl[0][0].s, acc[u], 0, 0, 0);
                acc[u] = __builtin_amdgcn_mfma_f32_16x16x32_bf16(f1.s, wh[0][1].s, acc[u], 0, 0, 0);
                acc[u] = __builtin_amdgcn_mfma_f32_16x16x32_bf16(f1.s, wl[0][1].s, acc[u], 0, 0, 0);
            } else {
                const int s2 = u - 4;
                acc[s2] = __builtin_amdgcn_mfma_f32_16x16x32_bf16(f0.s, wh[1][0].s, acc[s2], 0, 0, 0);
                acc[s2] = __builtin_amdgcn_mfma_f32_16x16x32_bf16(f0.s, wl[1][0].s, acc[s2], 0, 0, 0);
                acc[s2] = __builtin_amdgcn_mfma_f32_16x16x32_bf16(f1.s, wh[1][1].s, acc[s2], 0, 0, 0);
                acc[s2] = __builtin_amdgcn_mfma_f32_16x16x32_bf16(f1.s, wl[1][1].s, acc[s2], 0, 0, 0);
            }
        }

        // (4) transpose+write window k+2 into bank (k+2)%3 (== (k-1)%3, whose
        //     last reader finished at the end of iter k-1)
        if (k <= 2) { STAGE_WRITE(fv, (k + 2) % 3) }

        // (5) single barrier: window-k readers done; window k+2 visible
        if (k < 3) __syncthreads();
    }

    EPILOGUE(acc2[1], 3);
}

extern "C" void kernel_launch(void* const* d_in, const int* in_sizes, int n_in,
                              void* d_out, int out_size, void* d_ws, size_t ws_size,
                              hipStream_t stream) {
    const float* x = (const float*)d_in[0];
    const float* w = (const float*)d_in[1];
    float* out = (float*)d_out;
    conv_gate_wide<<<dim3(1024), dim3(256), 0, stream>>>(x, w, out);
}

// Round 8
// 120.435 us; speedup vs baseline: 1.0528x; 1.0278x over previous
//
#include <hip/hip_runtime.h>

// Causal dilated conv1d (dilation=64, K=2) + tanh*sigmoid gate via bf16 MFMA.
// v7 = v6 (3-bank ring, wide loads) + COUNTED-VMCNT PIPELINE (T3/T4):
//  - __syncthreads() compiles to s_waitcnt vmcnt(0)+s_barrier: 4x per block
//    the CU's whole VMEM queue drains to zero. Little's law: 6.3 TB/s needs
//    ~24 KB outstanding/CU at ~1us loaded latency; the saw-tooth leaves ~10-16
//    KB average == the observed 2.7 TB/s across v0-v6 regardless of
//    occupancy/width/barrier-count. Fix: raw s_barrier + lgkmcnt(0) only
//    (LDS visibility); load consumption uses compiler-counted vmcnt (never 0);
//    stores are never waited on inside the loop.
//  - 2-deep load pipeline: prologue issues W0..W3 (16 dwordx4 in flight),
//    W4 issued at iter-0 tail; every pack consumes loads >=1 iteration old.
//  - LDS swizzle S(rr)=(rr&7)^((rr>>3)&7) on write AND read: v6's 8-way
//    write conflict (row stride 128 B = 32 banks) -> 2-way (free).
// Ring: 3 banks x 64 rows x 64 ci bf16 = 24 KB; window w = rows
//   [t0-64+64w, t0+64w), bank w%3; chunk k reads windows k,k+1, writes W(k+2).
// Epilogue: tanh(y)*sigmoid(y) = (1-u)/(1+u^2), u=e^-y; transposed-output
//   MFMA (A=x,B=w) -> float4 stores; deferred one chunk for store cover.
// w split hi/lo (2 MFMA terms, fp32-grade w); x single RNE bf16.
// y[b,co,t] = sum_ci w[co][ci][0]*x[b][ci][t-64] + w[co][ci][1]*x[b][ci][t]

#define B_ 16
#define C_ 64
#define T_ 16384

typedef __attribute__((ext_vector_type(8))) short short8;
typedef __attribute__((ext_vector_type(4))) float f32x4;

union Frag { short8 s; unsigned u[4]; };

__device__ __forceinline__ unsigned bf16_rne(float f) {
    unsigned u = __float_as_uint(f);
    return (u + 0x7fffu + ((u >> 16) & 1u)) >> 16;
}

__device__ __forceinline__ unsigned pack_rne(float a, float b) {
    unsigned ua = __float_as_uint(a), ub = __float_as_uint(b);
    unsigned ra = ua + 0x7fffu + ((ua >> 16) & 1u);
    unsigned rb = ub + 0x7fffu + ((ub >> 16) & 1u);
    return (ra >> 16) | (rb & 0xffff0000u);
}

// Raw barrier: LDS visibility only — NO vmcnt drain (the whole point of v7).
#define LBAR()                                                              \
    do {                                                                    \
        asm volatile("s_waitcnt lgkmcnt(0)" ::: "memory");                  \
        __builtin_amdgcn_s_barrier();                                       \
    } while (0)

// Gate + store for chunk KK (transposed D): lane (m,q) holds t = KK*64+16s+4q+r
// of out row co = wid*16+m. tanh(y)*sigmoid(y) = (1-u)/(1+u^2), u=e^-y.
#define EPILOGUE(A, KK)                                                     \
    _Pragma("unroll")                                                       \
    for (int s = 0; s < 4; ++s) {                                           \
        float4 o4;                                                          \
        _Pragma("unroll")                                                   \
        for (int r = 0; r < 4; ++r) {                                       \
            float y = fmaxf((A)[s][r], -30.f);                              \
            float u = __expf(-y);                                           \
            ((float*)&o4)[r] = (1.f - u) *                                  \
                __builtin_amdgcn_rcpf(__builtin_fmaf(u, u, 1.f));           \
        }                                                                   \
        *(float4*)(ob + (KK) * 64 + 16 * s + 4 * q) = o4;                   \
    }

// In-register transpose of 4 float4 (4 ci x 4 t) -> 4x 8-B LDS writes.
// Row rr = 4*tq+e; swizzle S(rr)=(rr&7)^((rr>>3)&7) spreads same-slot lanes
// across 8 slots (2 lanes/slot = conflict-free). Read side uses the same S.
#define STAGE_WRITE(F, BANK)                                                \
    _Pragma("unroll")                                                       \
    for (int e = 0; e < 4; ++e) {                                           \
        const int rr = 4 * tq + e;                                          \
        const int sw = (rr & 7) ^ ((rr >> 3) & 7);                          \
        const int so = (BANK) * 4096 + rr * 64 +                            \
                       (((c4 >> 1) ^ sw) * 8) + ((c4 & 1) * 4);             \
        unsigned u0 = pack_rne(((const float*)&(F)[0])[e],                  \
                               ((const float*)&(F)[1])[e]);                 \
        unsigned u1 = pack_rne(((const float*)&(F)[2])[e],                  \
                               ((const float*)&(F)[3])[e]);                 \
        *(uint2*)(&xs[so]) = make_uint2(u0, u1);                            \
    }

__global__ __launch_bounds__(256, 4) void conv_gate_cnt(
    const float* __restrict__ x,
    const float* __restrict__ w,
    float* __restrict__ out)
{
    __shared__ unsigned short xs[3 * 64 * 64];   // 3 banks * 8 KB = 24576 B

    const int tid = threadIdx.x;
    const int bid = blockIdx.x;
    // XCD-bijective swizzle (1024 wgs, 8 XCDs).
    const int wg  = (bid & 7) * 128 + (bid >> 3);
    const int b   = wg >> 6;          // batch
    const int seg = wg & 63;          // 256-t segment
    const int t0  = seg << 8;
    const float* xb = x + (size_t)b * C_ * T_;

    // staging task: thread owns ci quad 4*c4..+3, t quad 4*tq..+3
    const int c4 = tid >> 4;          // 0..15
    const int tq = tid & 15;          // 0..15
    const float* xgb = xb + (size_t)(4 * c4) * T_ + 4 * tq;

    // ---- prologue: issue wide loads for W0..W3 (16 dwordx4 in flight)
    float4 fa[4], fb[4], fv[2][4];
    if (seg > 0) {
        #pragma unroll
        for (int i = 0; i < 4; ++i)
            fa[i] = *(const float4*)(xgb + (size_t)i * T_ + (t0 - 64));
    } else {
        #pragma unroll
        for (int i = 0; i < 4; ++i) fa[i] = make_float4(0.f, 0.f, 0.f, 0.f);
    }
    #pragma unroll
    for (int i = 0; i < 4; ++i)
        fb[i] = *(const float4*)(xgb + (size_t)i * T_ + t0);
    #pragma unroll
    for (int i = 0; i < 4; ++i)
        fv[0][i] = *(const float4*)(xgb + (size_t)i * T_ + (t0 + 64));
    #pragma unroll
    for (int i = 0; i < 4; ++i)
        fv[1][i] = *(const float4*)(xgb + (size_t)i * T_ + (t0 + 128));

    // ---- per-wave w fragments, hi/lo RNE split (covers x load latency)
    const int lane = tid & 63;
    const int wid  = tid >> 6;
    const int m    = lane & 15;
    const int q    = lane >> 4;
    const int co   = wid * 16 + m;

    Frag wh[2][2], wl[2][2];   // [tap p][k-half h]
    #pragma unroll
    for (int h = 0; h < 2; ++h) {
        const float* wp = w + co * 128 + h * 64 + q * 16;
        float f[16];
        #pragma unroll
        for (int v4 = 0; v4 < 4; ++v4) {
            float4 t4 = *(const float4*)(wp + 4 * v4);
            f[4*v4+0] = t4.x; f[4*v4+1] = t4.y; f[4*v4+2] = t4.z; f[4*v4+3] = t4.w;
        }
        #pragma unroll
        for (int p = 0; p < 2; ++p) {
            #pragma unroll
            for (int d = 0; d < 4; ++d) {
                float e0 = f[2*(2*d)   + p];
                float e1 = f[2*(2*d+1) + p];
                unsigned h0 = bf16_rne(e0), h1 = bf16_rne(e1);
                float r0 = e0 - __uint_as_float(h0 << 16);
                float r1 = e1 - __uint_as_float(h1 << 16);
                wh[p][h].u[d] = h0 | (h1 << 16);
                wl[p][h].u[d] = bf16_rne(r0) | (bf16_rne(r1) << 16);
            }
        }
    }

    // ---- prologue: stage W0,W1 into banks 0,1 (auto-counted vmcnt waits:
    //      fa packs with 12 loads still outstanding, fb with 8)
    STAGE_WRITE(fa, 0)
    STAGE_WRITE(fb, 1)

    float* ob = out + ((size_t)b * C_ + wid * 16 + m) * T_ + t0;   // transposed row

    f32x4 acc2[2][4];

    LBAR();

    // ---- 4 chunks of 64 t; raw barriers, no vmcnt drain anywhere.
    #pragma unroll
    for (int k = 0; k < 4; ++k) {
        // (1) deferred epilogue of chunk k-1 (stores pipeline freely)
        if (k >= 1) { EPILOGUE(acc2[(k & 1) ^ 1], k - 1); }

        // (2) compute chunk k: windows k (tap0), k+1 (tap1) in banks k%3,(k+1)%3
        f32x4* acc = acc2[k & 1];
        #pragma unroll
        for (int s = 0; s < 4; ++s) acc[s] = (f32x4){0.f, 0.f, 0.f, 0.f};
        #pragma unroll
        for (int u = 0; u < 8; ++u) {
            const int wnd  = k + (u >> 2);                 // compile-time
            const int rr_r = 16 * (u & 3) + m;             // row in window
            const int sw_r = (rr_r & 7) ^ ((rr_r >> 3) & 7);
            const int rbase = (wnd % 3) * 4096 + rr_r * 64;
            Frag f0, f1;
            f0.s = *(const short8*)(&xs[rbase + ((q ^ sw_r) * 8)]);        // ci 8q..
            f1.s = *(const short8*)(&xs[rbase + (((4 + q) ^ sw_r) * 8)]);  // ci 32+8q..
            if (u < 4) {
                acc[u] = __builtin_amdgcn_mfma_f32_16x16x32_bf16(f0.s, wh[0][0].s, acc[u], 0, 0, 0);
                acc[u] = __builtin_amdgcn_mfma_f32_16x16x32_bf16(f0.s, wl[0][0].s, acc[u], 0, 0, 0);
                acc[u] = __builtin_amdgcn_mfma_f32_16x16x32_bf16(f1.s, wh[0][1].s, acc[u], 0, 0, 0);
                acc[u] = __builtin_amdgcn_mfma_f32_16x16x32_bf16(f1.s, wl[0][1].s, acc[u], 0, 0, 0);
            } else {
                const int s2 = u - 4;
                acc[s2] = __builtin_amdgcn_mfma_f32_16x16x32_bf16(f0.s, wh[1][0].s, acc[s2], 0, 0, 0);
                acc[s2] = __builtin_amdgcn_mfma_f32_16x16x32_bf16(f0.s, wl[1][0].s, acc[s2], 0, 0, 0);
                acc[s2] = __builtin_amdgcn_mfma_f32_16x16x32_bf16(f1.s, wh[1][1].s, acc[s2], 0, 0, 0);
                acc[s2] = __builtin_amdgcn_mfma_f32_16x16x32_bf16(f1.s, wl[1][1].s, acc[s2], 0, 0, 0);
            }
        }

        // (3) stage W(k+2) from regs loaded >=1 iteration ago into bank (k+2)%3
        //     (auto-counted vmcnt: newer loads + epilogue stores stay in flight)
        if (k <= 2) { STAGE_WRITE(fv[k & 1], (k + 2) % 3) }

        // (3b) issue W4 loads into the buffer just packed (2-iteration cover)
        if (k == 0) {
            #pragma unroll
            for (int i = 0; i < 4; ++i)
                fv[0][i] = *(const float4*)(xgb + (size_t)i * T_ + (t0 + 192));
        }

        // (4) raw barrier: LDS writes visible, VMEM queue stays full
        if (k < 3) LBAR();
    }

    EPILOGUE(acc2[1], 3);
}

extern "C" void kernel_launch(void* const* d_in, const int* in_sizes, int n_in,
                              void* d_out, int out_size, void* d_ws, size_t ws_size,
                              hipStream_t stream) {
    const float* x = (const float*)d_in[0];
    const float* w = (const float*)d_in[1];
    float* out = (float*)d_out;
    conv_gate_cnt<<<dim3(1024), dim3(256), 0, stream>>>(x, w, out);
}